// Round 3
// baseline (5168.111 us; speedup 1.0000x reference)
//
#include <hip/hip_runtime.h>

// LatentExpander: 2-layer LSTM (H=128), B=512, SEQ=1024, out L=64.
// Inputs fp32, OUTPUT fp32. 32 blocks x 512 threads; 16 batch rows/block.
// ALL MFMA operands fp16; fp32 accumulators/state.
//
// R3 changes vs 3800us R2 (rocprof: VGPR_Count STILL 128 -> 224 persistent
// weight regs + working set ~280 > 256/wave hard cap at 8 waves/block on the
// UNIFIED gfx950 reg file; weights overflowed into ACC half + per-use copies,
// ~240 extra VALU/step, per-active-CU VALUBusy ~40%):
//  - weights NOT register-resident. Prep kernel converts them once to fp16
//    B-frag stream (448KB __device__ global, L2-resident per XCD). Main loop
//    streams frags via global_load_dwordx4, issued one phase ahead:
//      L0 MFMAs (b0 preloaded) -> issue b1(32) -> L0 epilogue -> bar ->
//      L1 MFMAs (b1)          -> issue b0'(24) -> L1 epilogue -> bar -> OP
//    Peak live regs ~175 -> honest fit in 256 budget, no AGPR copies.
//  - tanh via 2*rcp(1+exp(-2x))-1 (5 ops vs 8).
//
// MFMA 16x16x32 layout anchors (HW-verified; dtype-independent on gfx950):
//   A: lane holds A[m=l&15][k=(l>>4)*8+e]   (8 contig k, row-major LDS read)
//   B: lane holds B[k=(l>>4)*8+e][n=l&15]   = W[n][k], 8 contig k of row n
//   C/D: lane holds D[row=(l>>4)*4+r][col=l&15]

#define DI __device__ __forceinline__

typedef float f32x4 __attribute__((ext_vector_type(4)));
typedef _Float16 h16x4 __attribute__((ext_vector_type(4)));
typedef _Float16 h16x8 __attribute__((ext_vector_type(8)));

// fast sigmoid: 1 v_exp + 1 v_rcp (+mul/add). rcp ~1ulp; error << fp16 MFMA
// rounding already present in the gates.
DI float sigm_(float x) {
  float e = __expf(-x);
  return __builtin_amdgcn_rcpf(1.0f + e);
}
// fast tanh: 2*sigmoid(2x)-1 = 2*rcp(1+exp(-2x))-1. 5 VALU ops, no
// abs/copysign. Overflow-safe: exp(-2x)->inf => rcp(inf)=0 => -1 exactly.
DI float tanh_(float x) {
  float e = __expf(-2.0f * x);
  return __builtin_fmaf(2.0f, __builtin_amdgcn_rcpf(1.0f + e), -1.0f);
}
// load 8 consecutive fp32, round (RNE) to fp16 frag
DI h16x8 cvt8h(const float* __restrict__ p) {
  f32x4 a = *(const f32x4*)p;
  f32x4 b = *(const f32x4*)(p + 4);
  _Float16 t[8];
#pragma unroll
  for (int i = 0; i < 4; ++i) {
    t[i]     = (_Float16)a[i];
    t[4 + i] = (_Float16)b[i];
  }
  return *(h16x8*)t;
}

// ---------------- weight frag stream (global, L2-resident) ----------------
// element index = ((w*56 + slot)*64 + l)*8 halfs; slot 0..23 = L0 (kc*4+g),
// slot 24..55 = L1 (24 + kc*4+g). Per-wave region 56KB contiguous; each
// frag = 64 lanes x 16B, perfectly coalesced dwordx4 per lane.
__device__ __align__(16) _Float16 g_wstream[8 * 56 * 64 * 8];   // 448 KB

__global__ __launch_bounds__(512) void k_prep(
    const float* __restrict__ W_ih0, const float* __restrict__ W_hh0,
    const float* __restrict__ W_ih1, const float* __restrict__ W_hh1) {
  int gid = blockIdx.x * 512 + threadIdx.x;     // 56 blocks x 512 = 28672
  int l = gid & 63, s = (gid >> 6) % 56, w = gid / 3584;
  int l15 = l & 15, l4 = l >> 4;
  int g = s & 3;
  int n = g * 128 + 16 * w + l15;
  const float* src;
  if (s < 24) {                                 // L0: K=192
    int kc = s >> 2, k0 = kc * 32 + l4 * 8;
    src = (k0 < 128) ? (W_hh0 + n * 128 + k0)
                     : (W_ih0 + n * 320 + (k0 - 128));
  } else {                                      // L1: K=256
    int kc = (s - 24) >> 2, k0 = kc * 32 + l4 * 8;
    src = (k0 < 128) ? (W_ih1 + n * 128 + k0)
                     : (W_hh1 + n * 128 + (k0 - 128));
  }
  *(h16x8*)&g_wstream[(unsigned)gid * 8] = cvt8h(src);
}

// ---------------- LDS map (bytes) ----------------
// H0: 2 bufs x 16 rows x 400 B (cols 0..127 h0, 128..191 h_prev) = 12800
// H1: 2 bufs x 16 x 272 = 8704                          [12800, 21504)
// WO: out-proj B-frag stream, 16 frags x 64 lanes x 16 = [21504, 37888)
// XZ: fp16, 512 thr x 32 B = 16384                      [37888, 54272)
// OB: out ring, 2 steps x 16 rows x 64 f32 = 8192       [54272, 62464)
// B1: compact layer-1 bias, 512 f32 = 2048              [62464, 64512)
// BO: out bias, 64 f32 = 256                            [64512, 64768)
// AZ: prologue z-tile 16 x 528 = 8448 — OVERLAPS XZ region (barrier-ordered)
#define L_H0 0
#define L_H1 12800
#define L_WO 21504
#define L_XZ 37888
#define L_OB 54272
#define L_B1 62464
#define L_BO 64512
#define L_AZ 37888
#define L_TOT 64768
static_assert(L_TOT <= 65536, "LDS budget");

// One time step; P = ping-pong phase (compile-time -> immediate LDS bases).
// b0 holds this step's L0 B-frags on entry; refilled for the next step after
// L1's MFMAs (full OP phase + barriers of lead time before next use).
template <int P>
DI void lstm_step(unsigned char* smem, const _Float16* __restrict__ wsp,
                  h16x8 (&b0)[24], f32x4& c0r, f32x4& c1r,
                  int a0off, int a1off, int xzoff, int v16,
                  int w0off, int w1off, int oboff,
                  int col, int wv, int t, float* outp0) {
  constexpr int h0r = L_H0 + P * 6400, h0w = L_H0 + 6400 - P * 6400;
  constexpr int h1r = L_H1 + P * 4352, h1w = L_H1 + 4352 - P * 4352;

  // === layer 0: gates = [h0_old | h_prev] x W + xz ===
  f32x4 acc[4];
#pragma unroll
  for (int g = 0; g < 4; ++g) {
    h16x4 xv = *(const h16x4*)(smem + L_XZ + g * 4096 + xzoff);
    f32x4 a;
#pragma unroll
    for (int r = 0; r < 4; ++r) a[r] = (float)xv[r];
    acc[g] = a;
  }
#pragma unroll
  for (int kc = 0; kc < 6; ++kc) {
    h16x8 af = *(const h16x8*)(smem + h0r + a0off + kc * 64);
#pragma unroll
    for (int g = 0; g < 4; ++g)
      acc[g] = __builtin_amdgcn_mfma_f32_16x16x32_f16(af, b0[kc * 4 + g],
                                                      acc[g], 0, 0, 0);
  }
  // issue layer-1 B-frag loads now (b0 regs dead; in flight through the
  // L0 epilogue; ~full epilogue+barrier of L2 latency cover)
  h16x8 b1[32];
#pragma unroll
  for (int s = 0; s < 32; ++s)
    b1[s] = *(const h16x8*)(wsp + (24 + s) * 512);
#pragma unroll
  for (int r = 0; r < 4; ++r) {
    float ig = sigm_(acc[0][r]), fg = sigm_(acc[1][r]);
    float gg = tanh_(acc[2][r]), og = sigm_(acc[3][r]);
    c0r[r] = fg * c0r[r] + ig * gg;
    *(_Float16*)(smem + h0w + w0off + r * 400) = (_Float16)(og * tanh_(c0r[r]));
  }
  __syncthreads();                              // h0(t) visible

  // === layer 1: gates = [h0_new | h1_old] x W + (b_ih1+b_hh1) ===
#pragma unroll
  for (int g = 0; g < 4; ++g) {
    float bg = *(const float*)(smem + L_B1 + (g * 128 + col) * 4);
    f32x4 a = {bg, bg, bg, bg};
    acc[g] = a;
  }
#pragma unroll
  for (int kc = 0; kc < 8; ++kc) {
    h16x8 af = (kc < 4)
        ? *(const h16x8*)(smem + h0w + a0off + kc * 64)
        : *(const h16x8*)(smem + h1r + a1off + (kc - 4) * 64);
#pragma unroll
    for (int g = 0; g < 4; ++g)
      acc[g] = __builtin_amdgcn_mfma_f32_16x16x32_f16(af, b1[kc * 4 + g],
                                                      acc[g], 0, 0, 0);
  }
  // refill b0 for the NEXT step (b1 regs dead; covers OP phase + 2 barriers)
#pragma unroll
  for (int s = 0; s < 24; ++s)
    b0[s] = *(const h16x8*)(wsp + s * 512);
#pragma unroll
  for (int r = 0; r < 4; ++r) {
    float ig = sigm_(acc[0][r]), fg = sigm_(acc[1][r]);
    float gg = tanh_(acc[2][r]), og = sigm_(acc[3][r]);
    c1r[r] = fg * c1r[r] + ig * gg;
    *(_Float16*)(smem + h1w + w1off + r * 272) = (_Float16)(og * tanh_(c1r[r]));
  }
  __syncthreads();                              // h1(t) visible

  // === out-proj (waves 0-3): h_t = tanh(h1_new x W_out^T + b_out) ===
  // writes LDS only: OB ring (this step's 16x64 f32) + h_prev fp16.
  if (wv < 4) {
    float bo = *(const float*)(smem + L_BO + col * 4);
    f32x4 ao = {bo, bo, bo, bo};
#pragma unroll
    for (int kc = 0; kc < 4; ++kc) {
      h16x8 af  = *(const h16x8*)(smem + h1w + a1off + kc * 64);
      h16x8 bfr = *(const h16x8*)(smem + L_WO + kc * 4096 + v16);
      ao = __builtin_amdgcn_mfma_f32_16x16x32_f16(af, bfr, ao, 0, 0, 0);
    }
#pragma unroll
    for (int r = 0; r < 4; ++r) {
      float v = tanh_(ao[r]);
      *(float*)(smem + L_OB + oboff + r * 512 + P * 256) = v;   // out ring
      *(_Float16*)(smem + h0w + w0off + r * 400 + 256) = (_Float16)v;  // h_prev
    }
  }
  __syncthreads();                              // h_prev(t) + OB visible

  // === coalesced flush every other step: 2 t-steps x 16 rows x 64 j ===
  if (P) {
    f32x4 vv = *(const f32x4*)(smem + L_OB + v16);
    *(f32x4*)(outp0 + (unsigned)(t - 1) * 64u) = vv;
  }
}

__global__ __launch_bounds__(512, 2) void k_main(
    const float* __restrict__ z,
    const float* __restrict__ W_init_h, const float* __restrict__ b_init_h,
    const float* __restrict__ W_init_c, const float* __restrict__ b_init_c,
    const float* __restrict__ W_ih0, const float* __restrict__ W_hh0,
    const float* __restrict__ b_ih0, const float* __restrict__ b_hh0,
    const float* __restrict__ W_ih1, const float* __restrict__ W_hh1,
    const float* __restrict__ b_ih1, const float* __restrict__ b_hh1,
    const float* __restrict__ W_out, const float* __restrict__ b_out,
    float* __restrict__ out) {
  __shared__ __align__(16) unsigned char smem[L_TOT];
  const int tid = threadIdx.x;
  const int w = tid >> 6, l = tid & 63;
  const int l15 = l & 15, l4 = l >> 4;
  const int bl = blockIdx.x, b0i = bl << 4;
  const int col = 16 * w + l15;                 // owned gate/hidden col 0..127

  // ---------- prologue stage 1: fills ----------
  {
    // z tile -> AZ fp16: rows m=0..15, 256 cols, stride 528 B
    int zm = tid >> 5, zk = (tid & 31) * 8;
    *(h16x8*)(smem + L_AZ + zm * 528 + zk * 2) = cvt8h(z + (b0i + zm) * 256 + zk);
    // W_out -> per-wave frag stream: frag f=kc*4+wv, lane l holds
    // W_out[n=16*wv+(l&15)][k=kc*32+(l>>4)*8 .. +8]
    for (int i = tid; i < 1024; i += 512) {
      int li = i & 63, f = i >> 6;
      int kc = f >> 2, wv = f & 3;
      int n = 16 * wv + (li & 15), k0 = kc * 32 + ((li >> 4) & 3) * 8;
      *(h16x8*)(smem + L_WO + i * 16) = cvt8h(W_out + n * 128 + k0);
    }
    // compact bias tables
    *(float*)(smem + L_B1 + tid * 4) = b_ih1[tid] + b_hh1[tid];
    if (tid < 64) *(float*)(smem + L_BO + tid * 4) = b_out[tid];
    // zero h_prev cols (128..191) of H0 buffer 0
    if (tid < 256) {
      int r2 = tid >> 4, c2 = (tid & 15) * 4;
      h16x4 zz = {(_Float16)0, (_Float16)0, (_Float16)0, (_Float16)0};
      *(h16x4*)(smem + L_H0 + r2 * 400 + 256 + c2 * 2) = zz;
    }
  }
  __syncthreads();                              // AZ / WO / B1 / BO visible

  // ---------- prologue stage 2: MFMA prep GEMMs (reads AZ) ----------
  // xz[m][n] = z[m,:]·W_ih0[n,64:] + b_ih0[n]+b_hh0[n]   (n = g*128+col)
  // h/c init[m][layer*128+col] = z[m,:]·W_init_{h,c}[n,:] + b
  float c0i[4], c1i[4];
  f32x4 xza[4];
  {
    f32x4 ha[2], ca[2];
#pragma unroll
    for (int g = 0; g < 4; ++g) {
      float b = b_ih0[g * 128 + col] + b_hh0[g * 128 + col];
      f32x4 a = {b, b, b, b}; xza[g] = a;
    }
#pragma unroll
    for (int layer = 0; layer < 2; ++layer) {
      float bh = b_init_h[layer * 128 + col];
      float bc = b_init_c[layer * 128 + col];
      f32x4 ah = {bh, bh, bh, bh}; ha[layer] = ah;
      f32x4 ac = {bc, bc, bc, bc}; ca[layer] = ac;
    }
#pragma unroll
    for (int kc = 0; kc < 8; ++kc) {
      h16x8 az = *(const h16x8*)(smem + L_AZ + l15 * 528 + kc * 64 + l4 * 16);
      int kofs = kc * 32 + l4 * 8;
#pragma unroll
      for (int g = 0; g < 4; ++g) {
        h16x8 bz = cvt8h(W_ih0 + (g * 128 + col) * 320 + 64 + kofs);
        xza[g] = __builtin_amdgcn_mfma_f32_16x16x32_f16(az, bz, xza[g], 0, 0, 0);
      }
#pragma unroll
      for (int layer = 0; layer < 2; ++layer) {
        h16x8 bh = cvt8h(W_init_h + (layer * 128 + col) * 256 + kofs);
        ha[layer] = __builtin_amdgcn_mfma_f32_16x16x32_f16(az, bh, ha[layer], 0, 0, 0);
        h16x8 bc = cvt8h(W_init_c + (layer * 128 + col) * 256 + kofs);
        ca[layer] = __builtin_amdgcn_mfma_f32_16x16x32_f16(az, bc, ca[layer], 0, 0, 0);
      }
    }
    // h-init -> H0/H1 buffer 0 ; c stays in registers
#pragma unroll
    for (int r = 0; r < 4; ++r) {
      int m = l4 * 4 + r;
      *(_Float16*)(smem + L_H0 + m * 400 + col * 2) = (_Float16)ha[0][r];
      *(_Float16*)(smem + L_H1 + m * 272 + col * 2) = (_Float16)ha[1][r];
    }
#pragma unroll
    for (int r = 0; r < 4; ++r) { c0i[r] = ca[0][r]; c1i[r] = ca[1][r]; }
  }
  __syncthreads();                              // all AZ reads done
  // xz -> LDS fp16 (overwrites AZ region — safe after barrier)
#pragma unroll
  for (int g = 0; g < 4; ++g) {
    _Float16 t[4];
#pragma unroll
    for (int r = 0; r < 4; ++r) t[r] = (_Float16)xza[g][r];
    *(h16x4*)(smem + L_XZ + g * 4096 + tid * 8) = *(h16x4*)t;
  }

  f32x4 c0r, c1r;
#pragma unroll
  for (int r = 0; r < 4; ++r) { c0r[r] = c0i[r]; c1r[r] = c1i[r]; }

  // per-lane LDS offsets (affine in tid — cheap for regalloc to remat)
  const int a0off = l15 * 400 + l4 * 16;        // A-frag read within H0 buf
  const int a1off = l15 * 272 + l4 * 16;        // A-frag read within H1 buf
  const int xzoff = tid * 8;                    // XZ h16x4 (+g*4096)
  const int v16   = tid * 16;                   // WO frag read / OB flush read
  const int w0off = (l4 * 4) * 400 + col * 2;   // h0 write (+r*400)
  const int w1off = (l4 * 4) * 272 + col * 2;   // h1 write (+r*272)
  const int oboff = (l4 * 4) * 512 + col * 4;   // OB write (+r*512, +P*256)
  float* outp0 = out + (unsigned long long)(b0i + (tid >> 5)) * 65536ull +
                 ((tid * 4) & 127);

  // per-wave/lane base into the weight frag stream; slot s at wsp + s*512
  const _Float16* wsp = g_wstream + ((unsigned)w * 28672 + (unsigned)l * 8);
  // preload first step's L0 B-frags
  h16x8 b0[24];
#pragma unroll
  for (int s = 0; s < 24; ++s)
    b0[s] = *(const h16x8*)(wsp + s * 512);

  __syncthreads();                              // h-init / xz visible

  // ---------- time loop (unrolled x2: compile-time ping-pong) ----------
  for (int t2 = 0; t2 < 1024; t2 += 2) {
    lstm_step<0>(smem, wsp, b0, c0r, c1r, a0off, a1off, xzoff, v16,
                 w0off, w1off, oboff, col, w, t2, outp0);
    lstm_step<1>(smem, wsp, b0, c0r, c1r, a0off, a1off, xzoff, v16,
                 w0off, w1off, oboff, col, w, t2 + 1, outp0);
  }
}

// ---------------- launch ----------------
extern "C" void kernel_launch(void* const* d_in, const int* in_sizes, int n_in,
                              void* d_out, int out_size, void* d_ws, size_t ws_size,
                              hipStream_t stream) {
  (void)in_sizes; (void)n_in; (void)out_size; (void)d_ws; (void)ws_size;
  const float* z        = (const float*)d_in[0];
  // d_in[1] = seq_len (int scalar) == 1024, hardcoded
  const float* W_init_h = (const float*)d_in[2];
  const float* b_init_h = (const float*)d_in[3];
  const float* W_init_c = (const float*)d_in[4];
  const float* b_init_c = (const float*)d_in[5];
  const float* W_ih0 = (const float*)d_in[6];
  const float* W_hh0 = (const float*)d_in[7];
  const float* b_ih0 = (const float*)d_in[8];
  const float* b_hh0 = (const float*)d_in[9];
  const float* W_ih1 = (const float*)d_in[10];
  const float* W_hh1 = (const float*)d_in[11];
  const float* b_ih1 = (const float*)d_in[12];
  const float* b_hh1 = (const float*)d_in[13];
  const float* W_out = (const float*)d_in[14];
  const float* b_out = (const float*)d_in[15];
  float* out = (float*)d_out;

  k_prep<<<dim3(56), dim3(512), 0, stream>>>(W_ih0, W_hh0, W_ih1, W_hh1);
  k_main<<<dim3(32), dim3(512), 0, stream>>>(
      z, W_init_h, b_init_h, W_init_c, b_init_c,
      W_ih0, W_hh0, b_ih0, b_hh0, W_ih1, W_hh1, b_ih1, b_hh1,
      W_out, b_out, out);
}

// Round 4
// 2679.740 us; speedup vs baseline: 1.9286x; 1.9286x over previous
//
#include <hip/hip_runtime.h>

// LatentExpander: 2-layer LSTM (H=128), B=512, SEQ=1024, out L=64.
// Inputs fp32, OUTPUT fp32. Single persistent kernel, no workspace.
// 32 blocks x 512 threads; 16 batch rows/block. ALL MFMA operands fp16;
// fp32 accumulators/state.
//
// R4 changes vs R2(3800us)/R3(5050us regression):
//  - R3 proved streaming is dead: per-CU L2-return BW (~60B/cy) floors
//    458KB/step at ~3.2us/step. Weights must be resident.
//  - Full residency needs ~310 regs/wave > 256 unified cap (8 waves/CU)
//    -> every prior round overflowed into AGPR-copies/scratch (hidden
//    streaming). R4 closes the gap: 8 of 56 B-frags per wave (L1 kc=6,7)
//    live in LDS (64KB region; we have 95KB spare), read per step via
//    conflict-free ds_read_b128. Register demand: 192 weight + 16 acc +
//    8 c + ~30 working ~= 246 <= 256. No scratch, no loop global loads.
//  - LDS total 130,304 B (<=128KiB, known-good static size).
//
// MFMA 16x16x32 layout anchors (HW-verified; dtype-independent on gfx950):
//   A: lane holds A[m=l&15][k=(l>>4)*8+e]   (8 contig k, row-major LDS read)
//   B: lane holds B[k=(l>>4)*8+e][n=l&15]   = W[n][k], 8 contig k of row n
//   C/D: lane holds D[row=(l>>4)*4+r][col=l&15]

#define DI __device__ __forceinline__

typedef float f32x4 __attribute__((ext_vector_type(4)));
typedef _Float16 h16x4 __attribute__((ext_vector_type(4)));
typedef _Float16 h16x8 __attribute__((ext_vector_type(8)));

// fast sigmoid: 1 v_exp + 1 v_rcp (+mul/add). rcp ~1ulp; error << fp16 MFMA
// rounding already present in the gates.
DI float sigm_(float x) {
  float e = __expf(-x);
  return __builtin_amdgcn_rcpf(1.0f + e);
}
// fast tanh: 2*sigmoid(2x)-1 = 2*rcp(1+exp(-2x))-1. Overflow-safe:
// exp(-2x)->inf => rcp(inf)=0 => -1 exactly.
DI float tanh_(float x) {
  float e = __expf(-2.0f * x);
  return __builtin_fmaf(2.0f, __builtin_amdgcn_rcpf(1.0f + e), -1.0f);
}
// load 8 consecutive fp32, round (RNE) to fp16 frag
DI h16x8 cvt8h(const float* __restrict__ p) {
  f32x4 a = *(const f32x4*)p;
  f32x4 b = *(const f32x4*)(p + 4);
  _Float16 t[8];
#pragma unroll
  for (int i = 0; i < 4; ++i) {
    t[i]     = (_Float16)a[i];
    t[4 + i] = (_Float16)b[i];
  }
  return *(h16x8*)t;
}

// ---------------- LDS map (bytes) ----------------
// H0: 2 bufs x 16 rows x 400 B (cols 0..127 h0, 128..191 h_prev) = 12800
// H1: 2 bufs x 16 x 272 = 8704                          [12800, 21504)
// WO: out-proj B-frag stream, 16 frags x 64 lanes x 16 = [21504, 37888)
// XZ: fp16, 512 thr x 32 B = 16384                      [37888, 54272)
// OB: out ring, 2 steps x 16 rows x 64 f32 = 8192       [54272, 62464)
// B1: compact layer-1 bias, 512 f32 = 2048              [62464, 64512)
// BO: out bias, 64 f32 = 256                            [64512, 64768)
// WL: L1 kc6,7 B-frags, 8 waves x 8 frags x 64 x 16     [64768, 130304)
// AZ: prologue z-tile 16 x 528 = 8448 — OVERLAPS XZ region (barrier-ordered)
#define L_H0 0
#define L_H1 12800
#define L_WO 21504
#define L_XZ 37888
#define L_OB 54272
#define L_B1 62464
#define L_BO 64512
#define L_WL 64768
#define L_AZ 37888
#define L_TOT 130304
static_assert(L_TOT <= 131072, "LDS budget");

// One time step; P = ping-pong phase (compile-time -> immediate LDS bases).
template <int P>
DI void lstm_step(unsigned char* smem,
                  const h16x8 (&wf0)[24], const h16x8 (&wf1)[24],
                  f32x4& c0r, f32x4& c1r,
                  int a0off, int a1off, int xzoff, int v16, int wlb,
                  int w0off, int w1off, int oboff,
                  int col, int wv, int t, float* outp0) {
  constexpr int h0r = L_H0 + P * 6400, h0w = L_H0 + 6400 - P * 6400;
  constexpr int h1r = L_H1 + P * 4352, h1w = L_H1 + 4352 - P * 4352;

  // === layer 0: gates = [h0_old | h_prev] x W + xz ===
  f32x4 acc[4];
#pragma unroll
  for (int g = 0; g < 4; ++g) {
    h16x4 xv = *(const h16x4*)(smem + L_XZ + g * 4096 + xzoff);
    f32x4 a;
#pragma unroll
    for (int r = 0; r < 4; ++r) a[r] = (float)xv[r];
    acc[g] = a;
  }
#pragma unroll
  for (int kc = 0; kc < 6; ++kc) {
    h16x8 af = *(const h16x8*)(smem + h0r + a0off + kc * 64);
#pragma unroll
    for (int g = 0; g < 4; ++g)
      acc[g] = __builtin_amdgcn_mfma_f32_16x16x32_f16(af, wf0[kc * 4 + g],
                                                      acc[g], 0, 0, 0);
  }
#pragma unroll
  for (int r = 0; r < 4; ++r) {
    float ig = sigm_(acc[0][r]), fg = sigm_(acc[1][r]);
    float gg = tanh_(acc[2][r]), og = sigm_(acc[3][r]);
    c0r[r] = fg * c0r[r] + ig * gg;
    *(_Float16*)(smem + h0w + w0off + r * 400) = (_Float16)(og * tanh_(c0r[r]));
  }
  __syncthreads();                              // h0(t) visible

  // === layer 1: gates = [h0_new | h1_old] x W + (b_ih1+b_hh1) ===
  // kc 0..5 B-frags from registers; kc 6,7 from LDS (WL region).
#pragma unroll
  for (int g = 0; g < 4; ++g) {
    float bg = *(const float*)(smem + L_B1 + (g * 128 + col) * 4);
    f32x4 a = {bg, bg, bg, bg};
    acc[g] = a;
  }
#pragma unroll
  for (int kc = 0; kc < 8; ++kc) {
    h16x8 af = (kc < 4)
        ? *(const h16x8*)(smem + h0w + a0off + kc * 64)
        : *(const h16x8*)(smem + h1r + a1off + (kc - 4) * 64);
#pragma unroll
    for (int g = 0; g < 4; ++g) {
      h16x8 bf;
      if (kc < 6) bf = wf1[kc * 4 + g];
      else bf = *(const h16x8*)(smem + wlb + ((kc - 6) * 4 + g) * 1024);
      acc[g] = __builtin_amdgcn_mfma_f32_16x16x32_f16(af, bf, acc[g], 0, 0, 0);
    }
  }
#pragma unroll
  for (int r = 0; r < 4; ++r) {
    float ig = sigm_(acc[0][r]), fg = sigm_(acc[1][r]);
    float gg = tanh_(acc[2][r]), og = sigm_(acc[3][r]);
    c1r[r] = fg * c1r[r] + ig * gg;
    *(_Float16*)(smem + h1w + w1off + r * 272) = (_Float16)(og * tanh_(c1r[r]));
  }
  __syncthreads();                              // h1(t) visible

  // === out-proj (waves 0-3): h_t = tanh(h1_new x W_out^T + b_out) ===
  // writes LDS only: OB ring (this step's 16x64 f32) + h_prev fp16.
  if (wv < 4) {
    float bo = *(const float*)(smem + L_BO + col * 4);
    f32x4 ao = {bo, bo, bo, bo};
#pragma unroll
    for (int kc = 0; kc < 4; ++kc) {
      h16x8 af  = *(const h16x8*)(smem + h1w + a1off + kc * 64);
      h16x8 bfr = *(const h16x8*)(smem + L_WO + kc * 4096 + v16);
      ao = __builtin_amdgcn_mfma_f32_16x16x32_f16(af, bfr, ao, 0, 0, 0);
    }
#pragma unroll
    for (int r = 0; r < 4; ++r) {
      float v = tanh_(ao[r]);
      *(float*)(smem + L_OB + oboff + r * 512 + P * 256) = v;   // out ring
      *(_Float16*)(smem + h0w + w0off + r * 400 + 256) = (_Float16)v;  // h_prev
    }
  }
  __syncthreads();                              // h_prev(t) + OB visible

  // === coalesced flush every other step: 2 t-steps x 16 rows x 64 j ===
  // Store retires during next step's layer-0 (off the barrier-adjacent path).
  if (P) {
    f32x4 vv = *(const f32x4*)(smem + L_OB + v16);
    *(f32x4*)(outp0 + (unsigned)(t - 1) * 64u) = vv;
  }
}

__global__ __launch_bounds__(512, 2) void k_main(
    const float* __restrict__ z,
    const float* __restrict__ W_init_h, const float* __restrict__ b_init_h,
    const float* __restrict__ W_init_c, const float* __restrict__ b_init_c,
    const float* __restrict__ W_ih0, const float* __restrict__ W_hh0,
    const float* __restrict__ b_ih0, const float* __restrict__ b_hh0,
    const float* __restrict__ W_ih1, const float* __restrict__ W_hh1,
    const float* __restrict__ b_ih1, const float* __restrict__ b_hh1,
    const float* __restrict__ W_out, const float* __restrict__ b_out,
    float* __restrict__ out) {
  __shared__ __align__(16) unsigned char smem[L_TOT];
  const int tid = threadIdx.x;
  const int w = tid >> 6, l = tid & 63;
  const int l15 = l & 15, l4 = l >> 4;
  const int bl = blockIdx.x, b0i = bl << 4;
  const int col = 16 * w + l15;                 // owned gate/hidden col 0..127

  // ---------- prologue stage 1: fills ----------
  {
    // z tile -> AZ fp16: rows m=0..15, 256 cols, stride 528 B
    int zm = tid >> 5, zk = (tid & 31) * 8;
    *(h16x8*)(smem + L_AZ + zm * 528 + zk * 2) = cvt8h(z + (b0i + zm) * 256 + zk);
    // W_out -> per-wave frag stream: frag f=kc*4+wv, lane l holds
    // W_out[n=16*wv+(l&15)][k=kc*32+(l>>4)*8 .. +8]
    for (int i = tid; i < 1024; i += 512) {
      int li = i & 63, f = i >> 6;
      int kc = f >> 2, wv = f & 3;
      int n = 16 * wv + (li & 15), k0 = kc * 32 + ((li >> 4) & 3) * 8;
      *(h16x8*)(smem + L_WO + i * 16) = cvt8h(W_out + n * 128 + k0);
    }
    // WL: L1 kc=6,7 B-frags for this wave (k0-128 in [64,128) -> W_hh1)
#pragma unroll
    for (int f = 0; f < 8; ++f) {
      int kc = 6 + (f >> 2), g = f & 3;
      int n = g * 128 + col, k0 = kc * 32 + l4 * 8 - 128;
      *(h16x8*)(smem + L_WL + ((w * 8 + f) * 64 + l) * 16) =
          cvt8h(W_hh1 + n * 128 + k0);
    }
    // compact bias tables
    *(float*)(smem + L_B1 + tid * 4) = b_ih1[tid] + b_hh1[tid];
    if (tid < 64) *(float*)(smem + L_BO + tid * 4) = b_out[tid];
    // zero h_prev cols (128..191) of H0 buffer 0
    if (tid < 256) {
      int r2 = tid >> 4, c2 = (tid & 15) * 4;
      h16x4 zz = {(_Float16)0, (_Float16)0, (_Float16)0, (_Float16)0};
      *(h16x4*)(smem + L_H0 + r2 * 400 + 256 + c2 * 2) = zz;
    }
  }
  __syncthreads();                              // AZ / WO / WL / B1 / BO visible

  // ---------- prologue stage 2: MFMA prep GEMMs (reads AZ) ----------
  // xz[m][n] = z[m,:]·W_ih0[n,64:] + b_ih0[n]+b_hh0[n]   (n = g*128+col)
  // h/c init[m][layer*128+col] = z[m,:]·W_init_{h,c}[n,:] + b
  float c0i[4], c1i[4];
  f32x4 xza[4];
  {
    f32x4 ha[2], ca[2];
#pragma unroll
    for (int g = 0; g < 4; ++g) {
      float b = b_ih0[g * 128 + col] + b_hh0[g * 128 + col];
      f32x4 a = {b, b, b, b}; xza[g] = a;
    }
#pragma unroll
    for (int layer = 0; layer < 2; ++layer) {
      float bh = b_init_h[layer * 128 + col];
      float bc = b_init_c[layer * 128 + col];
      f32x4 ah = {bh, bh, bh, bh}; ha[layer] = ah;
      f32x4 ac = {bc, bc, bc, bc}; ca[layer] = ac;
    }
#pragma unroll
    for (int kc = 0; kc < 8; ++kc) {
      h16x8 az = *(const h16x8*)(smem + L_AZ + l15 * 528 + kc * 64 + l4 * 16);
      int kofs = kc * 32 + l4 * 8;
#pragma unroll
      for (int g = 0; g < 4; ++g) {
        h16x8 bz = cvt8h(W_ih0 + (g * 128 + col) * 320 + 64 + kofs);
        xza[g] = __builtin_amdgcn_mfma_f32_16x16x32_f16(az, bz, xza[g], 0, 0, 0);
      }
#pragma unroll
      for (int layer = 0; layer < 2; ++layer) {
        h16x8 bh = cvt8h(W_init_h + (layer * 128 + col) * 256 + kofs);
        ha[layer] = __builtin_amdgcn_mfma_f32_16x16x32_f16(az, bh, ha[layer], 0, 0, 0);
        h16x8 bc = cvt8h(W_init_c + (layer * 128 + col) * 256 + kofs);
        ca[layer] = __builtin_amdgcn_mfma_f32_16x16x32_f16(az, bc, ca[layer], 0, 0, 0);
      }
    }
    // h-init -> H0/H1 buffer 0 ; c stays in registers
#pragma unroll
    for (int r = 0; r < 4; ++r) {
      int m = l4 * 4 + r;
      *(_Float16*)(smem + L_H0 + m * 400 + col * 2) = (_Float16)ha[0][r];
      *(_Float16*)(smem + L_H1 + m * 272 + col * 2) = (_Float16)ha[1][r];
    }
#pragma unroll
    for (int r = 0; r < 4; ++r) { c0i[r] = ca[0][r]; c1i[r] = ca[1][r]; }
  }
  __syncthreads();                              // all AZ reads done
  // xz -> LDS fp16 (overwrites AZ region — safe after barrier)
#pragma unroll
  for (int g = 0; g < 4; ++g) {
    _Float16 t[4];
#pragma unroll
    for (int r = 0; r < 4; ++r) t[r] = (_Float16)xza[g][r];
    *(h16x4*)(smem + L_XZ + g * 4096 + tid * 8) = *(h16x4*)t;
  }

  // ---------- persistent weights into VGPR/AGPR B-frags (fp16) ----------
  // L0 (K=192): k<128 -> W_hh0[n][k] (h0_old); k in [128,192) -> W_ih0[n][k-128]
  // L1 kc0..5 (K=192 of 256): k<128 -> W_ih1[n][k]; k in [128,192) -> W_hh1
  h16x8 wf0[24], wf1[24];
#pragma unroll
  for (int kc = 0; kc < 6; ++kc)
#pragma unroll
    for (int g = 0; g < 4; ++g) {
      int n = g * 128 + col, k0 = kc * 32 + l4 * 8;
      const float* src = (k0 < 128) ? (W_hh0 + n * 128 + k0)
                                    : (W_ih0 + n * 320 + (k0 - 128));
      wf0[kc * 4 + g] = cvt8h(src);
    }
#pragma unroll
  for (int kc = 0; kc < 6; ++kc)
#pragma unroll
    for (int g = 0; g < 4; ++g) {
      int n = g * 128 + col, k0 = kc * 32 + l4 * 8;
      const float* src = (k0 < 128) ? (W_ih1 + n * 128 + k0)
                                    : (W_hh1 + n * 128 + (k0 - 128));
      wf1[kc * 4 + g] = cvt8h(src);
    }

  f32x4 c0r, c1r;
#pragma unroll
  for (int r = 0; r < 4; ++r) { c0r[r] = c0i[r]; c1r[r] = c1i[r]; }

  // per-lane LDS offsets (affine in tid — cheap for regalloc to remat)
  const int a0off = l15 * 400 + l4 * 16;        // A-frag read within H0 buf
  const int a1off = l15 * 272 + l4 * 16;        // A-frag read within H1 buf
  const int xzoff = tid * 8;                    // XZ h16x4 (+g*4096)
  const int v16   = tid * 16;                   // WO frag read / OB flush read
  const int wlb   = L_WL + (w * 8 * 64 + l) * 16;  // WL frag base (+f*1024)
  const int w0off = (l4 * 4) * 400 + col * 2;   // h0 write (+r*400)
  const int w1off = (l4 * 4) * 272 + col * 2;   // h1 write (+r*272)
  const int oboff = (l4 * 4) * 512 + col * 4;   // OB write (+r*512, +P*256)
  float* outp0 = out + (unsigned long long)(b0i + (tid >> 5)) * 65536ull +
                 ((tid * 4) & 127);
  __syncthreads();                              // h-init / xz visible

  // ---------- time loop (unrolled x2: compile-time ping-pong) ----------
  for (int t2 = 0; t2 < 1024; t2 += 2) {
    lstm_step<0>(smem, wf0, wf1, c0r, c1r, a0off, a1off, xzoff, v16, wlb,
                 w0off, w1off, oboff, col, w, t2, outp0);
    lstm_step<1>(smem, wf0, wf1, c0r, c1r, a0off, a1off, xzoff, v16, wlb,
                 w0off, w1off, oboff, col, w, t2 + 1, outp0);
  }
}

// ---------------- launch ----------------
extern "C" void kernel_launch(void* const* d_in, const int* in_sizes, int n_in,
                              void* d_out, int out_size, void* d_ws, size_t ws_size,
                              hipStream_t stream) {
  (void)in_sizes; (void)n_in; (void)out_size; (void)d_ws; (void)ws_size;
  const float* z        = (const float*)d_in[0];
  // d_in[1] = seq_len (int scalar) == 1024, hardcoded
  const float* W_init_h = (const float*)d_in[2];
  const float* b_init_h = (const float*)d_in[3];
  const float* W_init_c = (const float*)d_in[4];
  const float* b_init_c = (const float*)d_in[5];
  const float* W_ih0 = (const float*)d_in[6];
  const float* W_hh0 = (const float*)d_in[7];
  const float* b_ih0 = (const float*)d_in[8];
  const float* b_hh0 = (const float*)d_in[9];
  const float* W_ih1 = (const float*)d_in[10];
  const float* W_hh1 = (const float*)d_in[11];
  const float* b_ih1 = (const float*)d_in[12];
  const float* b_hh1 = (const float*)d_in[13];
  const float* W_out = (const float*)d_in[14];
  const float* b_out = (const float*)d_in[15];
  float* out = (float*)d_out;

  k_main<<<dim3(32), dim3(512), 0, stream>>>(
      z, W_init_h, b_init_h, W_init_c, b_init_c,
      W_ih0, W_hh0, b_ih0, b_hh0, W_ih1, W_hh1, b_ih1, b_hh1,
      W_out, b_out, out);
}

// Round 7
// 2575.332 us; speedup vs baseline: 2.0068x; 1.0405x over previous
//
#include <hip/hip_runtime.h>

// LatentExpander: 2-layer LSTM (H=128), B=512, SEQ=1024, out L=64.
// Inputs fp32, OUTPUT fp32. Single persistent kernel, no workspace.
// 32 blocks x 512 threads; 16 batch rows/block. ALL MFMA operands fp16;
// fp32 accumulators/state. INTRINSIC MFMAs only (compiler-managed hazards).
//
// R7 vs R5/R6 (both FAILED, absmax ~0.3, fences didn't help): the inline-asm
// AGPR-direct MFMA path is abandoned — two rounds, no diagnosis, identical
// failure. Reverted to R4's passing kernel (2679us).
// R7 vs R4: close the register over-subscription honestly. R4 demand:
// 192 weight regs + ~68 working ~= 260 > 256/wave cap (8 waves, unified
// file) -> per-step scratch churn (FETCH_SIZE excess ~6.4MB). R7 moves 4
// more frags (L0 kc=5) into the LDS weight region: 12 slots/wave, 98,304B.
// Demand ~176+68 = 244 <= 256 -> no spills; MFMA reads resident frags
// directly (intrinsic operands are AV-class; no copies when fitting).
// LDS total 163,072 <= 163,840 (160KiB pool, 1 block/CU).
//
// MFMA 16x16x32 layout anchors (HW-verified; dtype-independent on gfx950):
//   A: lane holds A[m=l&15][k=(l>>4)*8+e]   (8 contig k, row-major LDS read)
//   B: lane holds B[k=(l>>4)*8+e][n=l&15]   = W[n][k], 8 contig k of row n
//   C/D: lane holds D[row=(l>>4)*4+r][col=l&15]

#define DI __device__ __forceinline__

typedef float f32x4 __attribute__((ext_vector_type(4)));
typedef _Float16 h16x4 __attribute__((ext_vector_type(4)));
typedef _Float16 h16x8 __attribute__((ext_vector_type(8)));

// fast sigmoid: 1 v_exp + 1 v_rcp (+mul/add). rcp ~1ulp; error << fp16 MFMA
// rounding already present in the gates.
DI float sigm_(float x) {
  float e = __expf(-x);
  return __builtin_amdgcn_rcpf(1.0f + e);
}
// fast tanh: 2*sigmoid(2x)-1 = 2*rcp(1+exp(-2x))-1. Overflow-safe:
// exp(-2x)->inf => rcp(inf)=0 => -1 exactly.
DI float tanh_(float x) {
  float e = __expf(-2.0f * x);
  return __builtin_fmaf(2.0f, __builtin_amdgcn_rcpf(1.0f + e), -1.0f);
}
// load 8 consecutive fp32, round (RNE) to fp16 frag
DI h16x8 cvt8h(const float* __restrict__ p) {
  f32x4 a = *(const f32x4*)p;
  f32x4 b = *(const f32x4*)(p + 4);
  _Float16 t[8];
#pragma unroll
  for (int i = 0; i < 4; ++i) {
    t[i]     = (_Float16)a[i];
    t[4 + i] = (_Float16)b[i];
  }
  return *(h16x8*)t;
}

// ---------------- LDS map (bytes) ----------------
// H0: 2 bufs x 16 rows x 400 B (cols 0..127 h0, 128..191 h_prev) = 12800
// H1: 2 bufs x 16 x 272 = 8704                          [12800, 21504)
// WO: out-proj B-frag stream, 16 frags x 64 lanes x 16 = [21504, 37888)
// XZ: fp16, 512 thr x 32 B = 16384                      [37888, 54272)
// OB: out ring, 2 steps x 16 rows x 64 f32 = 8192       [54272, 62464)
// B1: compact layer-1 bias, 512 f32 = 2048              [62464, 64512)
// BO: out bias, 64 f32 = 256                            [64512, 64768)
// WL: LDS weight frags, 8 waves x 12 slots x 64 x 16    [64768, 163072)
//     slots 0..3 = L0 kc5 (g=0..3); 4..7 = L1 kc6; 8..11 = L1 kc7
// AZ: prologue z-tile 16 x 528 = 8448 — OVERLAPS XZ region (barrier-ordered)
#define L_H0 0
#define L_H1 12800
#define L_WO 21504
#define L_XZ 37888
#define L_OB 54272
#define L_B1 62464
#define L_BO 64512
#define L_WL 64768
#define L_AZ 37888
#define L_TOT 163072
static_assert(L_TOT <= 163840, "LDS budget (160 KiB/CU)");

// One time step; P = ping-pong phase (compile-time -> immediate LDS bases).
template <int P>
DI void lstm_step(unsigned char* smem,
                  const h16x8 (&wf0)[20], const h16x8 (&wf1)[24],
                  f32x4& c0r, f32x4& c1r,
                  int a0off, int a1off, int xzoff, int v16, int wlb,
                  int w0off, int w1off, int oboff,
                  int col, int wv, int t, float* outp0) {
  constexpr int h0r = L_H0 + P * 6400, h0w = L_H0 + 6400 - P * 6400;
  constexpr int h1r = L_H1 + P * 4352, h1w = L_H1 + 4352 - P * 4352;

  // === layer 0: gates = [h0_old | h_prev] x W + xz ===
  f32x4 acc[4];
#pragma unroll
  for (int g = 0; g < 4; ++g) {
    h16x4 xv = *(const h16x4*)(smem + L_XZ + g * 4096 + xzoff);
    f32x4 a;
#pragma unroll
    for (int r = 0; r < 4; ++r) a[r] = (float)xv[r];
    acc[g] = a;
  }
#pragma unroll
  for (int kc = 0; kc < 6; ++kc) {
    h16x8 af = *(const h16x8*)(smem + h0r + a0off + kc * 64);
#pragma unroll
    for (int g = 0; g < 4; ++g) {
      h16x8 bf = (kc < 5)
          ? wf0[kc * 4 + g]
          : *(const h16x8*)(smem + wlb + g * 1024);          // slots 0..3
      acc[g] = __builtin_amdgcn_mfma_f32_16x16x32_f16(af, bf, acc[g], 0, 0, 0);
    }
  }
#pragma unroll
  for (int r = 0; r < 4; ++r) {
    float ig = sigm_(acc[0][r]), fg = sigm_(acc[1][r]);
    float gg = tanh_(acc[2][r]), og = sigm_(acc[3][r]);
    c0r[r] = fg * c0r[r] + ig * gg;
    *(_Float16*)(smem + h0w + w0off + r * 400) = (_Float16)(og * tanh_(c0r[r]));
  }
  __syncthreads();                              // h0(t) visible

  // === layer 1: gates = [h0_new | h1_old] x W + (b_ih1+b_hh1) ===
  // kc 0..5 B-frags from registers; kc 6,7 from LDS (slots 4..11).
#pragma unroll
  for (int g = 0; g < 4; ++g) {
    float bg = *(const float*)(smem + L_B1 + (g * 128 + col) * 4);
    f32x4 a = {bg, bg, bg, bg};
    acc[g] = a;
  }
#pragma unroll
  for (int kc = 0; kc < 8; ++kc) {
    h16x8 af = (kc < 4)
        ? *(const h16x8*)(smem + h0w + a0off + kc * 64)
        : *(const h16x8*)(smem + h1r + a1off + (kc - 4) * 64);
#pragma unroll
    for (int g = 0; g < 4; ++g) {
      h16x8 bf = (kc < 6)
          ? wf1[kc * 4 + g]
          : *(const h16x8*)(smem + wlb + ((kc - 6) * 4 + g + 4) * 1024);
      acc[g] = __builtin_amdgcn_mfma_f32_16x16x32_f16(af, bf, acc[g], 0, 0, 0);
    }
  }
#pragma unroll
  for (int r = 0; r < 4; ++r) {
    float ig = sigm_(acc[0][r]), fg = sigm_(acc[1][r]);
    float gg = tanh_(acc[2][r]), og = sigm_(acc[3][r]);
    c1r[r] = fg * c1r[r] + ig * gg;
    *(_Float16*)(smem + h1w + w1off + r * 272) = (_Float16)(og * tanh_(c1r[r]));
  }
  __syncthreads();                              // h1(t) visible

  // === out-proj (waves 0-3): h_t = tanh(h1_new x W_out^T + b_out) ===
  // writes LDS only: OB ring (this step's 16x64 f32) + h_prev fp16.
  if (wv < 4) {
    float bo = *(const float*)(smem + L_BO + col * 4);
    f32x4 ao = {bo, bo, bo, bo};
#pragma unroll
    for (int kc = 0; kc < 4; ++kc) {
      h16x8 af  = *(const h16x8*)(smem + h1w + a1off + kc * 64);
      h16x8 bfr = *(const h16x8*)(smem + L_WO + kc * 4096 + v16);
      ao = __builtin_amdgcn_mfma_f32_16x16x32_f16(af, bfr, ao, 0, 0, 0);
    }
#pragma unroll
    for (int r = 0; r < 4; ++r) {
      float v = tanh_(ao[r]);
      *(float*)(smem + L_OB + oboff + r * 512 + P * 256) = v;   // out ring
      *(_Float16*)(smem + h0w + w0off + r * 400 + 256) = (_Float16)v;  // h_prev
    }
  }
  __syncthreads();                              // h_prev(t) + OB visible

  // === coalesced flush every other step: 2 t-steps x 16 rows x 64 j ===
  // Store retires during next step's layer-0 (off the barrier-adjacent path).
  if (P) {
    f32x4 vv = *(const f32x4*)(smem + L_OB + v16);
    *(f32x4*)(outp0 + (unsigned)(t - 1) * 64u) = vv;
  }
}

__global__ __launch_bounds__(512, 2) void k_main(
    const float* __restrict__ z,
    const float* __restrict__ W_init_h, const float* __restrict__ b_init_h,
    const float* __restrict__ W_init_c, const float* __restrict__ b_init_c,
    const float* __restrict__ W_ih0, const float* __restrict__ W_hh0,
    const float* __restrict__ b_ih0, const float* __restrict__ b_hh0,
    const float* __restrict__ W_ih1, const float* __restrict__ W_hh1,
    const float* __restrict__ b_ih1, const float* __restrict__ b_hh1,
    const float* __restrict__ W_out, const float* __restrict__ b_out,
    float* __restrict__ out) {
  __shared__ __align__(16) unsigned char smem[L_TOT];
  const int tid = threadIdx.x;
  const int w = tid >> 6, l = tid & 63;
  const int l15 = l & 15, l4 = l >> 4;
  const int bl = blockIdx.x, b0i = bl << 4;
  const int col = 16 * w + l15;                 // owned gate/hidden col 0..127

  // ---------- prologue stage 1: fills ----------
  {
    // z tile -> AZ fp16: rows m=0..15, 256 cols, stride 528 B
    int zm = tid >> 5, zk = (tid & 31) * 8;
    *(h16x8*)(smem + L_AZ + zm * 528 + zk * 2) = cvt8h(z + (b0i + zm) * 256 + zk);
    // W_out -> per-wave frag stream: frag f=kc*4+wv, lane l holds
    // W_out[n=16*wv+(l&15)][k=kc*32+(l>>4)*8 .. +8]
    for (int i = tid; i < 1024; i += 512) {
      int li = i & 63, f = i >> 6;
      int kc = f >> 2, wv = f & 3;
      int n = 16 * wv + (li & 15), k0 = kc * 32 + ((li >> 4) & 3) * 8;
      *(h16x8*)(smem + L_WO + i * 16) = cvt8h(W_out + n * 128 + k0);
    }
    // WL: 12 LDS weight slots for this wave.
    //   f 0..3:  L0 kc5, g=f     -> W_ih0[n][32+l4*8 ..]   (k0=160..191)
    //   f 4..11: L1 kc6/7, g=f&3 -> W_hh1[n][kc*32+l4*8-128]
#pragma unroll
    for (int f = 0; f < 12; ++f) {
      int g = f & 3;
      int n = g * 128 + col;
      const float* src;
      if (f < 4) {
        src = W_ih0 + n * 320 + (32 + l4 * 8);
      } else {
        int kc = 6 + ((f - 4) >> 2);
        src = W_hh1 + n * 128 + (kc * 32 + l4 * 8 - 128);
      }
      *(h16x8*)(smem + L_WL + ((w * 12 + f) * 64 + l) * 16) = cvt8h(src);
    }
    // compact bias tables
    *(float*)(smem + L_B1 + tid * 4) = b_ih1[tid] + b_hh1[tid];
    if (tid < 64) *(float*)(smem + L_BO + tid * 4) = b_out[tid];
    // zero h_prev cols (128..191) of H0 buffer 0
    if (tid < 256) {
      int r2 = tid >> 4, c2 = (tid & 15) * 4;
      h16x4 zz = {(_Float16)0, (_Float16)0, (_Float16)0, (_Float16)0};
      *(h16x4*)(smem + L_H0 + r2 * 400 + 256 + c2 * 2) = zz;
    }
  }
  __syncthreads();                              // AZ / WO / WL / B1 / BO visible

  // ---------- prologue stage 2: MFMA prep GEMMs (reads AZ) ----------
  // xz[m][n] = z[m,:]·W_ih0[n,64:] + b_ih0[n]+b_hh0[n]   (n = g*128+col)
  // h/c init[m][layer*128+col] = z[m,:]·W_init_{h,c}[n,:] + b
  float c0i[4], c1i[4];
  f32x4 xza[4];
  {
    f32x4 ha[2], ca[2];
#pragma unroll
    for (int g = 0; g < 4; ++g) {
      float b = b_ih0[g * 128 + col] + b_hh0[g * 128 + col];
      f32x4 a = {b, b, b, b}; xza[g] = a;
    }
#pragma unroll
    for (int layer = 0; layer < 2; ++layer) {
      float bh = b_init_h[layer * 128 + col];
      float bc = b_init_c[layer * 128 + col];
      f32x4 ah = {bh, bh, bh, bh}; ha[layer] = ah;
      f32x4 ac = {bc, bc, bc, bc}; ca[layer] = ac;
    }
#pragma unroll
    for (int kc = 0; kc < 8; ++kc) {
      h16x8 az = *(const h16x8*)(smem + L_AZ + l15 * 528 + kc * 64 + l4 * 16);
      int kofs = kc * 32 + l4 * 8;
#pragma unroll
      for (int g = 0; g < 4; ++g) {
        h16x8 bz = cvt8h(W_ih0 + (g * 128 + col) * 320 + 64 + kofs);
        xza[g] = __builtin_amdgcn_mfma_f32_16x16x32_f16(az, bz, xza[g], 0, 0, 0);
      }
#pragma unroll
      for (int layer = 0; layer < 2; ++layer) {
        h16x8 bh = cvt8h(W_init_h + (layer * 128 + col) * 256 + kofs);
        ha[layer] = __builtin_amdgcn_mfma_f32_16x16x32_f16(az, bh, ha[layer], 0, 0, 0);
        h16x8 bc = cvt8h(W_init_c + (layer * 128 + col) * 256 + kofs);
        ca[layer] = __builtin_amdgcn_mfma_f32_16x16x32_f16(az, bc, ca[layer], 0, 0, 0);
      }
    }
    // h-init -> H0/H1 buffer 0 ; c stays in registers
#pragma unroll
    for (int r = 0; r < 4; ++r) {
      int m = l4 * 4 + r;
      *(_Float16*)(smem + L_H0 + m * 400 + col * 2) = (_Float16)ha[0][r];
      *(_Float16*)(smem + L_H1 + m * 272 + col * 2) = (_Float16)ha[1][r];
    }
#pragma unroll
    for (int r = 0; r < 4; ++r) { c0i[r] = ca[0][r]; c1i[r] = ca[1][r]; }
  }
  __syncthreads();                              // all AZ reads done
  // xz -> LDS fp16 (overwrites AZ region — safe after barrier)
#pragma unroll
  for (int g = 0; g < 4; ++g) {
    _Float16 t[4];
#pragma unroll
    for (int r = 0; r < 4; ++r) t[r] = (_Float16)xza[g][r];
    *(h16x4*)(smem + L_XZ + g * 4096 + tid * 8) = *(h16x4*)t;
  }

  // ---------- persistent weights -> register B-frags (fp16) ----------
  // L0 kc0..4 (K=160 of 192): k<128 -> W_hh0[n][k]; k in [128,160) -> W_ih0
  // L1 kc0..5 (K=192 of 256): k<128 -> W_ih1[n][k]; k in [128,192) -> W_hh1
  // 44 frags = 176 regs; total demand ~244 <= 256 -> honest fit, no spills.
  h16x8 wf0[20], wf1[24];
#pragma unroll
  for (int kc = 0; kc < 5; ++kc)
#pragma unroll
    for (int g = 0; g < 4; ++g) {
      int n = g * 128 + col, k0 = kc * 32 + l4 * 8;
      const float* src = (k0 < 128) ? (W_hh0 + n * 128 + k0)
                                    : (W_ih0 + n * 320 + (k0 - 128));
      wf0[kc * 4 + g] = cvt8h(src);
    }
#pragma unroll
  for (int kc = 0; kc < 6; ++kc)
#pragma unroll
    for (int g = 0; g < 4; ++g) {
      int n = g * 128 + col, k0 = kc * 32 + l4 * 8;
      const float* src = (k0 < 128) ? (W_ih1 + n * 128 + k0)
                                    : (W_hh1 + n * 128 + (k0 - 128));
      wf1[kc * 4 + g] = cvt8h(src);
    }

  f32x4 c0r, c1r;
#pragma unroll
  for (int r = 0; r < 4; ++r) { c0r[r] = c0i[r]; c1r[r] = c1i[r]; }

  // per-lane LDS offsets (affine in tid — cheap for regalloc to remat)
  const int a0off = l15 * 400 + l4 * 16;        // A-frag read within H0 buf
  const int a1off = l15 * 272 + l4 * 16;        // A-frag read within H1 buf
  const int xzoff = tid * 8;                    // XZ h16x4 (+g*4096)
  const int v16   = tid * 16;                   // WO frag read / OB flush read
  const int wlb   = L_WL + (w * 12 * 64 + l) * 16;  // WL frag base (+slot*1024)
  const int w0off = (l4 * 4) * 400 + col * 2;   // h0 write (+r*400)
  const int w1off = (l4 * 4) * 272 + col * 2;   // h1 write (+r*272)
  const int oboff = (l4 * 4) * 512 + col * 4;   // OB write (+r*512, +P*256)
  float* outp0 = out + (unsigned long long)(b0i + (tid >> 5)) * 65536ull +
                 ((tid * 4) & 127);
  __syncthreads();                              // h-init / xz visible

  // ---------- time loop (unrolled x2: compile-time ping-pong) ----------
  for (int t2 = 0; t2 < 1024; t2 += 2) {
    lstm_step<0>(smem, wf0, wf1, c0r, c1r, a0off, a1off, xzoff, v16, wlb,
                 w0off, w1off, oboff, col, w, t2, outp0);
    lstm_step<1>(smem, wf0, wf1, c0r, c1r, a0off, a1off, xzoff, v16, wlb,
                 w0off, w1off, oboff, col, w, t2 + 1, outp0);
  }
}

// ---------------- launch ----------------
extern "C" void kernel_launch(void* const* d_in, const int* in_sizes, int n_in,
                              void* d_out, int out_size, void* d_ws, size_t ws_size,
                              hipStream_t stream) {
  (void)in_sizes; (void)n_in; (void)out_size; (void)d_ws; (void)ws_size;
  const float* z        = (const float*)d_in[0];
  // d_in[1] = seq_len (int scalar) == 1024, hardcoded
  const float* W_init_h = (const float*)d_in[2];
  const float* b_init_h = (const float*)d_in[3];
  const float* W_init_c = (const float*)d_in[4];
  const float* b_init_c = (const float*)d_in[5];
  const float* W_ih0 = (const float*)d_in[6];
  const float* W_hh0 = (const float*)d_in[7];
  const float* b_ih0 = (const float*)d_in[8];
  const float* b_hh0 = (const float*)d_in[9];
  const float* W_ih1 = (const float*)d_in[10];
  const float* W_hh1 = (const float*)d_in[11];
  const float* b_ih1 = (const float*)d_in[12];
  const float* b_hh1 = (const float*)d_in[13];
  const float* W_out = (const float*)d_in[14];
  const float* b_out = (const float*)d_in[15];
  float* out = (float*)d_out;

  k_main<<<dim3(32), dim3(512), 0, stream>>>(
      z, W_init_h, b_init_h, W_init_c, b_init_c,
      W_ih0, W_hh0, b_ih0, b_hh0, W_ih1, W_hh1, b_ih1, b_hh1,
      W_out, b_out, out);
}

// Round 8
// 1818.446 us; speedup vs baseline: 2.8420x; 1.4162x over previous
//
#include <hip/hip_runtime.h>

// LatentExpander: 2-layer LSTM (H=128), B=512, SEQ=1024, out L=64.
// Inputs fp32, OUTPUT fp32. Single persistent kernel, no workspace.
// R8: 128 blocks x 512 threads; 4 batch rows/block at MFMA rows {0,4,8,12}.
// ALL MFMA operands fp16; fp32 accumulators/state. INTRINSIC MFMAs only.
//
// R8 vs R7 (2485us steady): counters showed VALU ~3360cy/step/active-CU,
// invariant across R2/R3/R4/R7 -> the LSTM epilogue (5 exp + 5 rcp per
// element, quarter-rate trans) with 4 elements/thread is the wall; MFMA
// only 32% busy; 224 CUs idle. R8 quarters the per-thread epilogue by
// quartering rows/block and mapping batch rows to MFMA rows {0,4,8,12}:
// every lane's acc[0] (C-row=4*l4) is a valid element -> 1 element/thread.
// Garbage rows (1-3,5-7,..) are finite (prologue-inited, never rewritten);
// MFMA row m depends only on A row m, so garbage never contaminates valid
// rows. Per-CU MFMA count unchanged; 128 CUs active. Reg/LDS same as R7.
//
// MFMA 16x16x32 layout anchors (HW-verified; dtype-independent on gfx950):
//   A: lane holds A[m=l&15][k=(l>>4)*8+e]   (8 contig k, row-major LDS read)
//   B: lane holds B[k=(l>>4)*8+e][n=l&15]   = W[n][k], 8 contig k of row n
//   C/D: lane holds D[row=(l>>4)*4+r][col=l&15]  (r=0 -> row 4*l4)

#define DI __device__ __forceinline__

typedef float f32x4 __attribute__((ext_vector_type(4)));
typedef _Float16 h16x4 __attribute__((ext_vector_type(4)));
typedef _Float16 h16x8 __attribute__((ext_vector_type(8)));

// fast sigmoid: 1 v_exp + 1 v_rcp (+mul/add). rcp ~1ulp; error << fp16 MFMA
// rounding already present in the gates.
DI float sigm_(float x) {
  float e = __expf(-x);
  return __builtin_amdgcn_rcpf(1.0f + e);
}
// fast tanh: 2*sigmoid(2x)-1 = 2*rcp(1+exp(-2x))-1. Overflow-safe:
// exp(-2x)->inf => rcp(inf)=0 => -1 exactly.
DI float tanh_(float x) {
  float e = __expf(-2.0f * x);
  return __builtin_fmaf(2.0f, __builtin_amdgcn_rcpf(1.0f + e), -1.0f);
}
// load 8 consecutive fp32, round (RNE) to fp16 frag
DI h16x8 cvt8h(const float* __restrict__ p) {
  f32x4 a = *(const f32x4*)p;
  f32x4 b = *(const f32x4*)(p + 4);
  _Float16 t[8];
#pragma unroll
  for (int i = 0; i < 4; ++i) {
    t[i]     = (_Float16)a[i];
    t[4 + i] = (_Float16)b[i];
  }
  return *(h16x8*)t;
}

// ---------------- LDS map (bytes) ----------------
// H0: 2 bufs x 16 rows x 400 B (cols 0..127 h0, 128..191 h_prev) = 12800
// H1: 2 bufs x 16 x 272 = 8704                          [12800, 21504)
// WO: out-proj B-frag stream, 16 frags x 64 lanes x 16 = [21504, 37888)
// XZ: fp16 h16x4/thread (4 gates), 512 x 8 B = 4096     [37888, 41984)
// OB: out ring, 2 steps x 4 rows x 64 f32 = 2048        [54272, 56320)
// B1: layer-1 bias f32x4/thread, 512 x 16 B = 8192      [56320, 64512)
// BO: out bias, 64 f32 = 256                            [64512, 64768)
// WL: LDS weight frags, 8 waves x 12 slots x 64 x 16    [64768, 163072)
//     slots 0..3 = L0 kc5 (g=0..3); 4..7 = L1 kc6; 8..11 = L1 kc7
// AZ: prologue z-tile 16 x 528 = 8448 — OVERLAPS XZ region (barrier-ordered)
#define L_H0 0
#define L_H1 12800
#define L_WO 21504
#define L_XZ 37888
#define L_OB 54272
#define L_B1 56320
#define L_BO 64512
#define L_WL 64768
#define L_AZ 37888
#define L_TOT 163072
static_assert(L_TOT <= 163840, "LDS budget (160 KiB/CU)");

// One time step; P = ping-pong phase (compile-time -> immediate LDS bases).
template <int P>
DI void lstm_step(unsigned char* smem,
                  const h16x8 (&wf0)[20], const h16x8 (&wf1)[24],
                  float& c0r, float& c1r,
                  int a0off, int a1off, int xzoff, int v16, int wlb,
                  int w0off, int w1off, int oboff, int obro,
                  int col, int wv, int t, float* outp0) {
  constexpr int h0r = L_H0 + P * 6400, h0w = L_H0 + 6400 - P * 6400;
  constexpr int h1r = L_H1 + P * 4352, h1w = L_H1 + 4352 - P * 4352;

  // === layer 0: gates = [h0_old | h_prev] x W + xz ===
  f32x4 acc[4];
  {
    h16x4 xv = *(const h16x4*)(smem + L_XZ + xzoff);   // 4 gates, this elem
#pragma unroll
    for (int g = 0; g < 4; ++g) {
      float v = (float)xv[g];
      f32x4 a = {v, v, v, v};                          // garbage rows: finite
      acc[g] = a;
    }
  }
#pragma unroll
  for (int kc = 0; kc < 6; ++kc) {
    h16x8 af = *(const h16x8*)(smem + h0r + a0off + kc * 64);
#pragma unroll
    for (int g = 0; g < 4; ++g) {
      h16x8 bf = (kc < 5)
          ? wf0[kc * 4 + g]
          : *(const h16x8*)(smem + wlb + g * 1024);          // slots 0..3
      acc[g] = __builtin_amdgcn_mfma_f32_16x16x32_f16(af, bf, acc[g], 0, 0, 0);
    }
  }
  {  // epilogue: ONE element (row 4*l4, col)
    float ig = sigm_(acc[0][0]), fg = sigm_(acc[1][0]);
    float gg = tanh_(acc[2][0]), og = sigm_(acc[3][0]);
    c0r = fg * c0r + ig * gg;
    *(_Float16*)(smem + h0w + w0off) = (_Float16)(og * tanh_(c0r));
  }
  __syncthreads();                              // h0(t) visible

  // === layer 1: gates = [h0_new | h1_old] x W + (b_ih1+b_hh1) ===
  // kc 0..5 B-frags from registers; kc 6,7 from LDS (slots 4..11).
  {
    f32x4 bv = *(const f32x4*)(smem + L_B1 + v16);
#pragma unroll
    for (int g = 0; g < 4; ++g) {
      f32x4 a = {bv[g], bv[g], bv[g], bv[g]};
      acc[g] = a;
    }
  }
#pragma unroll
  for (int kc = 0; kc < 8; ++kc) {
    h16x8 af = (kc < 4)
        ? *(const h16x8*)(smem + h0w + a0off + kc * 64)
        : *(const h16x8*)(smem + h1r + a1off + (kc - 4) * 64);
#pragma unroll
    for (int g = 0; g < 4; ++g) {
      h16x8 bf = (kc < 6)
          ? wf1[kc * 4 + g]
          : *(const h16x8*)(smem + wlb + ((kc - 6) * 4 + g + 4) * 1024);
      acc[g] = __builtin_amdgcn_mfma_f32_16x16x32_f16(af, bf, acc[g], 0, 0, 0);
    }
  }
  {  // epilogue: ONE element
    float ig = sigm_(acc[0][0]), fg = sigm_(acc[1][0]);
    float gg = tanh_(acc[2][0]), og = sigm_(acc[3][0]);
    c1r = fg * c1r + ig * gg;
    *(_Float16*)(smem + h1w + w1off) = (_Float16)(og * tanh_(c1r));
  }
  __syncthreads();                              // h1(t) visible

  // === out-proj (waves 0-3): h_t = tanh(h1_new x W_out^T + b_out) ===
  // writes LDS only: OB ring (4 rows x 64 f32) + h_prev fp16.
  if (wv < 4) {
    float bo = *(const float*)(smem + L_BO + col * 4);
    f32x4 ao = {bo, bo, bo, bo};
#pragma unroll
    for (int kc = 0; kc < 4; ++kc) {
      h16x8 af  = *(const h16x8*)(smem + h1w + a1off + kc * 64);
      h16x8 bfr = *(const h16x8*)(smem + L_WO + kc * 4096 + v16);
      ao = __builtin_amdgcn_mfma_f32_16x16x32_f16(af, bfr, ao, 0, 0, 0);
    }
    float v = tanh_(ao[0]);                     // ONE element (row 4*l4)
    *(float*)(smem + L_OB + P * 1024 + oboff) = v;          // out ring
    *(_Float16*)(smem + h0w + w0off + 256) = (_Float16)v;   // h_prev(t)
  }
  __syncthreads();                              // h_prev(t) + OB visible

  // === coalesced flush every other step: 2 t-steps x 4 rows x 64 j ===
  // thread tid -> (p2=tid>>8, row=(tid>>6)&3, j=tid&63); 256B runs.
  if (P) {
    float vv = *(const float*)(smem + L_OB + obro);
    *(outp0 + (unsigned)(t - 1) * 64u) = vv;    // outp0 includes +p2*64
  }
}

__global__ __launch_bounds__(512, 2) void k_main(
    const float* __restrict__ z,
    const float* __restrict__ W_init_h, const float* __restrict__ b_init_h,
    const float* __restrict__ W_init_c, const float* __restrict__ b_init_c,
    const float* __restrict__ W_ih0, const float* __restrict__ W_hh0,
    const float* __restrict__ b_ih0, const float* __restrict__ b_hh0,
    const float* __restrict__ W_ih1, const float* __restrict__ W_hh1,
    const float* __restrict__ b_ih1, const float* __restrict__ b_hh1,
    const float* __restrict__ W_out, const float* __restrict__ b_out,
    float* __restrict__ out) {
  __shared__ __align__(16) unsigned char smem[L_TOT];
  const int tid = threadIdx.x;
  const int w = tid >> 6, l = tid & 63;
  const int l15 = l & 15, l4 = l >> 4;
  const int bl = blockIdx.x, b0i = bl << 2;     // 4 batch rows/block
  const int col = 16 * w + l15;                 // owned gate/hidden col 0..127

  // ---------- prologue stage 1: fills ----------
  {
    // z tile -> AZ fp16: MFMA rows 4k get z[b0+k]; other rows zero.
    int zm = tid >> 5, zk = (tid & 31) * 8;
    h16x8 zv;
    if ((zm & 3) == 0) {
      zv = cvt8h(z + (b0i + (zm >> 2)) * 256 + zk);
    } else {
      _Float16 t[8] = {};
      zv = *(h16x8*)t;
    }
    *(h16x8*)(smem + L_AZ + zm * 528 + zk * 2) = zv;
    // W_out -> per-wave frag stream: frag f=kc*4+wv, lane l holds
    // W_out[n=16*wv+(l&15)][k=kc*32+(l>>4)*8 .. +8]
    for (int i = tid; i < 1024; i += 512) {
      int li = i & 63, f = i >> 6;
      int kc = f >> 2, wv = f & 3;
      int n = 16 * wv + (li & 15), k0 = kc * 32 + ((li >> 4) & 3) * 8;
      *(h16x8*)(smem + L_WO + i * 16) = cvt8h(W_out + n * 128 + k0);
    }
    // WL: 12 LDS weight slots for this wave.
    //   f 0..3:  L0 kc5, g=f     -> W_ih0[n][32+l4*8 ..]   (k0=160..191)
    //   f 4..11: L1 kc6/7, g=f&3 -> W_hh1[n][kc*32+l4*8-128]
#pragma unroll
    for (int f = 0; f < 12; ++f) {
      int g = f & 3;
      int n = g * 128 + col;
      const float* src;
      if (f < 4) {
        src = W_ih0 + n * 320 + (32 + l4 * 8);
      } else {
        int kc = 6 + ((f - 4) >> 2);
        src = W_hh1 + n * 128 + (kc * 32 + l4 * 8 - 128);
      }
      *(h16x8*)(smem + L_WL + ((w * 12 + f) * 64 + l) * 16) = cvt8h(src);
    }
    // bias tables: B1 f32x4 (4 gates) per thread; BO out bias
    {
      f32x4 bv;
#pragma unroll
      for (int g = 0; g < 4; ++g)
        bv[g] = b_ih1[g * 128 + col] + b_hh1[g * 128 + col];
      *(f32x4*)(smem + L_B1 + tid * 16) = bv;
    }
    if (tid < 64) *(float*)(smem + L_BO + tid * 4) = b_out[tid];
    // zero h_prev cols (128..191) of H0 buffer 0 — ALL 16 rows (finite)
    if (tid < 256) {
      int r2 = tid >> 4, c2 = (tid & 15) * 4;
      h16x4 zz = {(_Float16)0, (_Float16)0, (_Float16)0, (_Float16)0};
      *(h16x4*)(smem + L_H0 + r2 * 400 + 256 + c2 * 2) = zz;
    }
  }
  __syncthreads();                              // AZ / WO / WL / B1 / BO visible

  // ---------- prologue stage 2: MFMA prep GEMMs (reads AZ) ----------
  // xz[m][n] = z[m,:]·W_ih0[n,64:] + b_ih0[n]+b_hh0[n]   (n = g*128+col)
  // h/c init[m][layer*128+col] = z[m,:]·W_init_{h,c}[n,:] + b
  float c0i, c1i;
  f32x4 xza[4];
  {
    f32x4 ha[2], ca[2];
#pragma unroll
    for (int g = 0; g < 4; ++g) {
      float b = b_ih0[g * 128 + col] + b_hh0[g * 128 + col];
      f32x4 a = {b, b, b, b}; xza[g] = a;
    }
#pragma unroll
    for (int layer = 0; layer < 2; ++layer) {
      float bh = b_init_h[layer * 128 + col];
      float bc = b_init_c[layer * 128 + col];
      f32x4 ah = {bh, bh, bh, bh}; ha[layer] = ah;
      f32x4 ac = {bc, bc, bc, bc}; ca[layer] = ac;
    }
#pragma unroll
    for (int kc = 0; kc < 8; ++kc) {
      h16x8 az = *(const h16x8*)(smem + L_AZ + l15 * 528 + kc * 64 + l4 * 16);
      int kofs = kc * 32 + l4 * 8;
#pragma unroll
      for (int g = 0; g < 4; ++g) {
        h16x8 bz = cvt8h(W_ih0 + (g * 128 + col) * 320 + 64 + kofs);
        xza[g] = __builtin_amdgcn_mfma_f32_16x16x32_f16(az, bz, xza[g], 0, 0, 0);
      }
#pragma unroll
      for (int layer = 0; layer < 2; ++layer) {
        h16x8 bh = cvt8h(W_init_h + (layer * 128 + col) * 256 + kofs);
        ha[layer] = __builtin_amdgcn_mfma_f32_16x16x32_f16(az, bh, ha[layer], 0, 0, 0);
        h16x8 bc = cvt8h(W_init_c + (layer * 128 + col) * 256 + kofs);
        ca[layer] = __builtin_amdgcn_mfma_f32_16x16x32_f16(az, bc, ca[layer], 0, 0, 0);
      }
    }
    // h-init -> H0/H1 buffer 0, ALL 4 r rows (garbage rows finite, never
    // rewritten); c-state: valid element only (r=0 -> row 4*l4).
#pragma unroll
    for (int r = 0; r < 4; ++r) {
      int m = l4 * 4 + r;
      *(_Float16*)(smem + L_H0 + m * 400 + col * 2) = (_Float16)ha[0][r];
      *(_Float16*)(smem + L_H1 + m * 272 + col * 2) = (_Float16)ha[1][r];
    }
    c0i = ca[0][0]; c1i = ca[1][0];
  }
  __syncthreads();                              // all AZ reads done
  // xz -> LDS fp16, ONE element (r=0) x 4 gates per thread (overwrites AZ
  // region — safe after barrier)
  {
    _Float16 t[4];
#pragma unroll
    for (int g = 0; g < 4; ++g) t[g] = (_Float16)xza[g][0];
    *(h16x4*)(smem + L_XZ + tid * 8) = *(h16x4*)t;
  }

  // ---------- persistent weights -> register B-frags (fp16) ----------
  // L0 kc0..4 (K=160 of 192): k<128 -> W_hh0[n][k]; k in [128,160) -> W_ih0
  // L1 kc0..5 (K=192 of 256): k<128 -> W_ih1[n][k]; k in [128,192) -> W_hh1
  // 44 frags = 176 regs; total demand ~240 <= 256 -> honest fit, no spills.
  h16x8 wf0[20], wf1[24];
#pragma unroll
  for (int kc = 0; kc < 5; ++kc)
#pragma unroll
    for (int g = 0; g < 4; ++g) {
      int n = g * 128 + col, k0 = kc * 32 + l4 * 8;
      const float* src = (k0 < 128) ? (W_hh0 + n * 128 + k0)
                                    : (W_ih0 + n * 320 + (k0 - 128));
      wf0[kc * 4 + g] = cvt8h(src);
    }
#pragma unroll
  for (int kc = 0; kc < 6; ++kc)
#pragma unroll
    for (int g = 0; g < 4; ++g) {
      int n = g * 128 + col, k0 = kc * 32 + l4 * 8;
      const float* src = (k0 < 128) ? (W_ih1 + n * 128 + k0)
                                    : (W_hh1 + n * 128 + (k0 - 128));
      wf1[kc * 4 + g] = cvt8h(src);
    }

  float c0r = c0i, c1r = c1i;

  // per-lane LDS offsets (affine in tid — cheap for regalloc to remat)
  const int a0off = l15 * 400 + l4 * 16;        // A-frag read within H0 buf
  const int a1off = l15 * 272 + l4 * 16;        // A-frag read within H1 buf
  const int xzoff = tid * 8;                    // XZ h16x4 (4 gates)
  const int v16   = tid * 16;                   // WO / B1 read
  const int wlb   = L_WL + (w * 12 * 64 + l) * 16;  // WL frag base (+slot*1024)
  const int w0off = (4 * l4) * 400 + col * 2;   // h0 write (row 4*l4)
  const int w1off = (4 * l4) * 272 + col * 2;   // h1 write (row 4*l4)
  const int oboff = l4 * 256 + col * 4;         // OB write (+P*1024)
  const int obro  = (tid >> 8) * 1024 + ((tid >> 6) & 3) * 256 + (tid & 63) * 4;
  // flush: thread -> (p2, row, j); outp0 bakes in row, j, p2's time offset
  float* outp0 = out + (unsigned long long)(b0i + ((tid >> 6) & 3)) * 65536ull +
                 (tid >> 8) * 64 + (tid & 63);
  __syncthreads();                              // h-init / xz visible

  // ---------- time loop (unrolled x2: compile-time ping-pong) ----------
  for (int t2 = 0; t2 < 1024; t2 += 2) {
    lstm_step<0>(smem, wf0, wf1, c0r, c1r, a0off, a1off, xzoff, v16, wlb,
                 w0off, w1off, oboff, obro, col, w, t2, outp0);
    lstm_step<1>(smem, wf0, wf1, c0r, c1r, a0off, a1off, xzoff, v16, wlb,
                 w0off, w1off, oboff, obro, col, w, t2 + 1, outp0);
  }
}

// ---------------- launch ----------------
extern "C" void kernel_launch(void* const* d_in, const int* in_sizes, int n_in,
                              void* d_out, int out_size, void* d_ws, size_t ws_size,
                              hipStream_t stream) {
  (void)in_sizes; (void)n_in; (void)out_size; (void)d_ws; (void)ws_size;
  const float* z        = (const float*)d_in[0];
  // d_in[1] = seq_len (int scalar) == 1024, hardcoded
  const float* W_init_h = (const float*)d_in[2];
  const float* b_init_h = (const float*)d_in[3];
  const float* W_init_c = (const float*)d_in[4];
  const float* b_init_c = (const float*)d_in[5];
  const float* W_ih0 = (const float*)d_in[6];
  const float* W_hh0 = (const float*)d_in[7];
  const float* b_ih0 = (const float*)d_in[8];
  const float* b_hh0 = (const float*)d_in[9];
  const float* W_ih1 = (const float*)d_in[10];
  const float* W_hh1 = (const float*)d_in[11];
  const float* b_ih1 = (const float*)d_in[12];
  const float* b_hh1 = (const float*)d_in[13];
  const float* W_out = (const float*)d_in[14];
  const float* b_out = (const float*)d_in[15];
  float* out = (float*)d_out;

  k_main<<<dim3(128), dim3(512), 0, stream>>>(
      z, W_init_h, b_init_h, W_init_c, b_init_c,
      W_ih0, W_hh0, b_ih0, b_hh0, W_ih1, W_hh1, b_ih1, b_hh1,
      W_out, b_out, out);
}